// Round 14
// baseline (291.269 us; speedup 1.0000x reference)
//
#include <hip/hip_runtime.h>
#include <hip/hip_bf16.h>

// QuaternionLinear = one 8192x4096x4096 GEMM vs Hamilton-assembled W.
// Round 14 (= R13 with the nontemporal_load type fixed): A-operand DIRECT
// from global (pre-tiled fragment-linear xbt; coalesced global_load_dwordx4
// -> regs, counted-vmcnt 2-phase prefetch, L1 shares across the 4 waves per
// A-half). B via LDS (R4-proven swizzled staging + compiler ds_reads).
// Removes ~2/3 of LDS-port traffic (the R4-R12 co-bottleneck): LDS now
// 96 KB/tile (~750cyc) vs MFMA 2066cyc (32x32x16, layouts verified R11/R12).

#define M_DIM 8192
#define N_DIM 4096
#define K_DIM 4096
#define BK 64
#define NT (K_DIM / BK)   // 64 K-tiles

typedef __attribute__((ext_vector_type(8))) short bf16x8;
typedef __attribute__((ext_vector_type(4))) float f32x4;
typedef __attribute__((ext_vector_type(16))) float f32x16;
typedef __attribute__((ext_vector_type(8))) unsigned short ushort8;

static __device__ __forceinline__ unsigned short f2bf(float f) {
    unsigned int u = __float_as_uint(f);
    return (unsigned short)((u + 0x7fffu + ((u >> 16) & 1u)) >> 16);
}
static __device__ __forceinline__ unsigned short f2bf_sgn(float f, unsigned int sg) {
    unsigned int u = __float_as_uint(f) ^ sg;
    return (unsigned short)((u + 0x7fffu + ((u >> 16) & 1u)) >> 16);
}

// ---------------- prep: x (fp32) -> xbt (bf16, fragment-tiled) ----------------
// xbt layout: block (h = A-half 0..63, t = ktile 0..63) of 8192 elems:
// chunk c = (kc*4+mi)*64 + lane (16B each): elem j of chunk =
// x[h*128 + mi*32 + (lane&31)][t*64 + kc*16 + (lane>>5)*8 + j].
__global__ __launch_bounds__(256) void cvt_x_t(const float* __restrict__ x,
                                               unsigned short* __restrict__ xbt) {
    __shared__ unsigned short T[128][72];     // +8 pad: conflict-free both passes
    int bid = blockIdx.x;
    int h = bid >> 6, t = bid & 63;
    int tid = threadIdx.x;

    #pragma unroll
    for (int j = 0; j < 8; ++j) {
        int c = j * 256 + tid;                // 16 chunks of 4 fp32 per row
        int r = c >> 4, ko = (c & 15) * 4;
        f32x4 v = __builtin_nontemporal_load(
            (const f32x4*)(x + (size_t)(h * 128 + r) * 4096 + t * 64 + ko));
        T[r][ko + 0] = f2bf(v[0]); T[r][ko + 1] = f2bf(v[1]);
        T[r][ko + 2] = f2bf(v[2]); T[r][ko + 3] = f2bf(v[3]);
    }
    __syncthreads();
    #pragma unroll
    for (int i = 0; i < 4; ++i) {
        int c = i * 256 + tid;                // 0..1023 chunks out
        int ln = c & 63, mi = (c >> 6) & 3, kc = c >> 8;
        int row = mi * 32 + (ln & 31), k = kc * 16 + (ln >> 5) * 8;
        *(ushort8*)(xbt + (size_t)(h * 64 + t) * 8192 + (size_t)c * 8) =
            *(const ushort8*)&T[row][k];
    }
}

// ---------------- prep: assemble Hamilton W (bf16, row-major) ----------------
__global__ __launch_bounds__(256) void prep_w_kernel(const float* __restrict__ Wr,
    const float* __restrict__ Wi, const float* __restrict__ Wj,
    const float* __restrict__ Wk, unsigned short* __restrict__ wb) {
    int row = blockIdx.x >> 1;
    int col = ((blockIdx.x & 1) * 256 + threadIdx.x) * 8;
    int p = row >> 10, q = col >> 10;
    int ci = p ^ q;
    const float* src = (ci == 0) ? Wr : (ci == 1) ? Wi : (ci == 2) ? Wj : Wk;
    unsigned int sg = ((0x428Eu >> (p * 4 + q)) & 1u) << 31;
    int so = (row & 1023) * 1024 + (col & 1023);
    f32x4 a = *(const f32x4*)(src + so);
    f32x4 b = *(const f32x4*)(src + so + 4);
    ushort8 o;
    o[0] = f2bf_sgn(a[0], sg); o[1] = f2bf_sgn(a[1], sg);
    o[2] = f2bf_sgn(a[2], sg); o[3] = f2bf_sgn(a[3], sg);
    o[4] = f2bf_sgn(b[0], sg); o[5] = f2bf_sgn(b[1], sg);
    o[6] = f2bf_sgn(b[2], sg); o[7] = f2bf_sgn(b[3], sg);
    *(ushort8*)(wb + row * 4096 + col) = o;
}

// ---------------- main GEMM ----------------
#define GLD16(gp, lp) __builtin_amdgcn_global_load_lds( \
    (const __attribute__((address_space(1))) void*)(gp), \
    (__attribute__((address_space(3))) void*)(lp), 16, 0, 0)

#define BAR() do { asm volatile("" ::: "memory"); \
                   __builtin_amdgcn_s_barrier(); \
                   asm volatile("" ::: "memory"); } while (0)
#define SB()  __builtin_amdgcn_sched_barrier(0)
#define VM(n) do { asm volatile("s_waitcnt vmcnt(" #n ")" ::: "memory"); SB(); } while (0)

#define MF32(a, b, c) __builtin_amdgcn_mfma_f32_32x32x16_bf16(a, b, c, 0, 0, 0)

// 4 asm A-loads (one kc-phase): dst a{K}_0..3, per-lane 64-bit addr P,
// mi via imm offset. Early-clobber: dsts must not alias the addr pair.
#define ALOAD4(K, P) \
    asm volatile("global_load_dwordx4 %0, %4, off\n\t" \
                 "global_load_dwordx4 %1, %4, off offset:1024\n\t" \
                 "global_load_dwordx4 %2, %4, off offset:2048\n\t" \
                 "global_load_dwordx4 %3, %4, off offset:3072" \
        : "=&v"(a##K##_0), "=&v"(a##K##_1), "=&v"(a##K##_2), "=&v"(a##K##_3) \
        : "v"(P))

#define MFMA8(A0, A1, A2, A3, B0, B1) do { \
    __builtin_amdgcn_s_setprio(1); \
    acc[0][0] = MF32(A0, B0, acc[0][0]); acc[0][1] = MF32(A0, B1, acc[0][1]); \
    acc[1][0] = MF32(A1, B0, acc[1][0]); acc[1][1] = MF32(A1, B1, acc[1][1]); \
    acc[2][0] = MF32(A2, B0, acc[2][0]); acc[2][1] = MF32(A2, B1, acc[2][1]); \
    acc[3][0] = MF32(A3, B0, acc[3][0]); acc[3][1] = MF32(A3, B1, acc[3][1]); \
    __builtin_amdgcn_s_setprio(0); \
} while (0)

#define BREAD(KC) \
    bf16x8 b0 = *(const bf16x8*)(bb + (vB0 ^ ((KC) << 5))); \
    bf16x8 b1 = *(const bf16x8*)(bb + (vB0 ^ ((KC) << 5)) + 4096)

#define STAGEB(dstOff, tt) do { \
    const unsigned short* gb_ = Bg + (tt) * BK; \
    char* lb_ = (char*)Bsh + (dstOff); \
    _Pragma("unroll") \
    for (int i_ = 0; i_ < 4; ++i_) \
        GLD16(gb_ + soffB[i_], lb_ + (i_ * 512 + tid) * 16); \
} while (0)

__global__ __launch_bounds__(512, 2) void qgemm_bf16(
    const unsigned short* __restrict__ A, const unsigned short* __restrict__ B,
    const float* __restrict__ bias, float* __restrict__ out)
{
    // B-only LDS: 2 bufs x 32 KB. Content: slot s at row r = kslot s^(r&7)
    // (R4-proven 0-conflict staging+read pattern).
    __shared__ __align__(16) unsigned short Bsh[32768];

    int bid = blockIdx.x;
    int cpx = gridDim.x >> 3;                 // 512/8 = 64, bijective
    int wg  = (bid & 7) * cpx + (bid >> 3);
    int mt   = wg >> 4;                       // M-tile 0..31
    int bcol = (wg & 15) * 256;               // 16 N-tiles

    int tid  = threadIdx.x;
    int lane = tid & 63;
    int wid  = tid >> 6;                      // 0..7
    int hA   = wid >> 2;                      // 0..1: which 128-row A half
    int wn   = wid & 3;                       // 0..3: 64-col B band
    int l31  = lane & 31;
    int hi   = lane >> 5;

    // A: per-lane pointers for kc=0..3 of current tile (fragment-linear xbt).
    const char* pA0 = (const char*)A
        + (size_t)((mt * 2 + hA) * 64) * 16384 + lane * 16;
    const char* pA1 = pA0 + 4096;
    const char* pA2 = pA0 + 8192;
    const char* pA3 = pA0 + 12288;

    // B staging: src offsets (elements), t-independent.
    const unsigned short* Bg = B + (size_t)bcol * K_DIM;
    int soffB[4];
    #pragma unroll
    for (int i = 0; i < 4; ++i) {
        int c = i * 512 + tid;
        soffB[i] = (c >> 3) * K_DIM + (((c & 7) ^ ((c >> 3) & 7)) << 3);
    }

    // B read base (byte, kc=0): row = wn*64 + ni*32 + l31 (ni via +4096 imm),
    // byte-in-row = ((hi^e0)<<4) | (e21<<5); phase kc: ^ (kc<<5).
    unsigned vB0 = (unsigned)((wn * 64 + l31) * 128)
                 + (((unsigned)hi ^ (unsigned)(l31 & 1)) << 4)
                 + (((unsigned)(l31 >> 1) & 3u) << 5);
    unsigned rb = 0;                          // read-buffer byte offset

    f32x16 acc[4][2] = {};
    bf16x8 a0_0, a0_1, a0_2, a0_3;
    bf16x8 a1_0, a1_1, a1_2, a1_3;
    bf16x8 a2_0, a2_1, a2_2, a2_3;
    bf16x8 a3_0, a3_1, a3_2, a3_3;

    // Prologue: stage B(0) -> buf0; load A(t0,kc0), A(t0,kc1).
    STAGEB(0, 0);
    ALOAD4(0, pA0);
    ALOAD4(1, pA1);

    for (int t = 0; t < NT - 1; ++t) {
        const char* bb = (const char*)Bsh + rb;
        // ---- p0: issue kc2(t); wait abuf0; barrier (B(t) visible) ----
        ALOAD4(2, pA2);
        VM(8);
        BAR();
        { BREAD(0); MFMA8(a0_0, a0_1, a0_2, a0_3, b0, b1); }
        // ---- p1: issue kc3(t); stage B(t+1) -> other buf ----
        ALOAD4(3, pA3);
        STAGEB(rb ^ 0x8000u, t + 1);
        VM(12);
        { BREAD(1); MFMA8(a1_0, a1_1, a1_2, a1_3, b0, b1); }
        // ---- p2: issue kc0(t+1) ----
        pA0 += 16384;
        ALOAD4(0, pA0);
        VM(12);
        { BREAD(2); MFMA8(a2_0, a2_1, a2_2, a2_3, b0, b1); }
        // ---- p3: issue kc1(t+1) ----
        pA1 += 16384;
        ALOAD4(1, pA1);
        pA2 += 16384; pA3 += 16384;
        VM(12);
        { BREAD(3); MFMA8(a3_0, a3_1, a3_2, a3_3, b0, b1); }
        rb ^= 0x8000u;
    }
    // ---- peeled last tile: no further issues; tight vmcnt {8,8,4,0} ----
    {
        const char* bb = (const char*)Bsh + rb;
        ALOAD4(2, pA2);
        VM(8);
        BAR();
        { BREAD(0); MFMA8(a0_0, a0_1, a0_2, a0_3, b0, b1); }
        ALOAD4(3, pA3);
        VM(8);
        { BREAD(1); MFMA8(a1_0, a1_1, a1_2, a1_3, b0, b1); }
        VM(4);
        { BREAD(2); MFMA8(a2_0, a2_1, a2_2, a2_3, b0, b1); }
        VM(0);
        { BREAD(3); MFMA8(a3_0, a3_1, a3_2, a3_3, b0, b1); }
    }

    // epilogue: 32x32 C/D layout (verified): col = lane&31,
    // row = (reg&3) + 8*(reg>>2) + 4*(lane>>5).
    int brow = mt * 256;
    #pragma unroll
    for (int ni = 0; ni < 2; ++ni) {
        int col = bcol + wn * 64 + ni * 32 + l31;
        float bv = bias[col];
        #pragma unroll
        for (int mi = 0; mi < 4; ++mi) {
            int r0 = brow + hA * 128 + mi * 32 + 4 * hi;
            #pragma unroll
            for (int r = 0; r < 16; ++r) {
                int row = r0 + (r & 3) + 8 * (r >> 2);
                __builtin_nontemporal_store(acc[mi][ni][r] + bv,
                                            &out[(size_t)row * N_DIM + col]);
            }
        }
    }
}

// ---------------- fallback: reg-staged, no workspace (round-3, known-good) --
#define FBM 128
#define FBN 128
#define FBK 64
__global__ __launch_bounds__(256) void qgemm_fb(const float* __restrict__ x,
    const float* __restrict__ Wr, const float* __restrict__ Wi,
    const float* __restrict__ Wj, const float* __restrict__ Wk,
    const float* __restrict__ bias, float* __restrict__ out)
{
    __shared__ unsigned short As[FBM * FBK];
    __shared__ unsigned short Bs[FBN * FBK];

    int bid = blockIdx.x;
    int cpx = gridDim.x >> 3;
    int wg = (bid & 7) * cpx + (bid >> 3);
    int brow = (wg >> 5) * FBM;
    int bcol = (wg & 31) * FBN;

    int tid = threadIdx.x;
    int lane = tid & 63;
    int wv = tid >> 6;
    int wm = (wv >> 1) << 6;
    int wn = (wv & 1) << 6;
    int fr = lane & 15;
    int fk = (lane >> 4) << 3;

    int p = bcol >> 10;
    f32x4 acc[4][4] = {};

    for (int kt = 0; kt < K_DIM / FBK; ++kt) {
        int k0 = kt * FBK;
        int q = k0 >> 10;
        int ci = p ^ q;
        const float* wsrc = (ci == 0) ? Wr : (ci == 1) ? Wi : (ci == 2) ? Wj : Wk;
        unsigned int sg = ((0x428Eu >> (p * 4 + q)) & 1u) << 31;

        __syncthreads();
        #pragma unroll
        for (int i = 0; i < 4; ++i) {
            int c = i * 256 + tid;
            int row = c >> 3, colo = (c & 7) << 3;
            const float* s = x + (size_t)(brow + row) * K_DIM + k0 + colo;
            float4 a = *(const float4*)s;
            float4 b = *(const float4*)(s + 4);
            ushort8 o;
            o[0] = f2bf(a.x); o[1] = f2bf(a.y); o[2] = f2bf(a.z); o[3] = f2bf(a.w);
            o[4] = f2bf(b.x); o[5] = f2bf(b.y); o[6] = f2bf(b.z); o[7] = f2bf(b.w);
            *(ushort8*)(&As[c << 3]) = o;
        }
        #pragma unroll
        for (int i = 0; i < 4; ++i) {
            int c = i * 256 + tid;
            int row = c >> 3, colo = (c & 7) << 3;
            const float* s = wsrc + ((bcol + row) & 1023) * 1024 + ((k0 + colo) & 1023);
            float4 a = *(const float4*)s;
            float4 b = *(const float4*)(s + 4);
            ushort8 o;
            o[0] = f2bf_sgn(a.x, sg); o[1] = f2bf_sgn(a.y, sg);
            o[2] = f2bf_sgn(a.z, sg); o[3] = f2bf_sgn(a.w, sg);
            o[4] = f2bf_sgn(b.x, sg); o[5] = f2bf_sgn(b.y, sg);
            o[6] = f2bf_sgn(b.z, sg); o[7] = f2bf_sgn(b.w, sg);
            *(ushort8*)(&Bs[c << 3]) = o;
        }
        __syncthreads();

        #pragma unroll
        for (int ks = 0; ks < 2; ++ks) {
            bf16x8 af[4], bfr[4];
            #pragma unroll
            for (int m = 0; m < 4; ++m)
                af[m] = *(const bf16x8*)(&As[(wm + m * 16 + fr) * FBK + ks * 32 + fk]);
            #pragma unroll
            for (int n = 0; n < 4; ++n)
                bfr[n] = *(const bf16x8*)(&Bs[(wn + n * 16 + fr) * FBK + ks * 32 + fk]);
            #pragma unroll
            for (int m = 0; m < 4; ++m)
                #pragma unroll
                for (int n = 0; n < 4; ++n)
                    acc[m][n] = __builtin_amdgcn_mfma_f32_16x16x32_bf16(
                        af[m], bfr[n], acc[m][n], 0, 0, 0);
        }
    }

    int cr = (lane >> 4) << 2;
    int cc = lane & 15;
    #pragma unroll
    for (int n = 0; n < 4; ++n) {
        int col = bcol + wn + n * 16 + cc;
        float bv = bias[col];
        #pragma unroll
        for (int m = 0; m < 4; ++m) {
            int r0 = brow + wm + m * 16 + cr;
            #pragma unroll
            for (int r = 0; r < 4; ++r)
                out[(size_t)(r0 + r) * N_DIM + col] = acc[m][n][r] + bv;
        }
    }
}

extern "C" void kernel_launch(void* const* d_in, const int* in_sizes, int n_in,
                              void* d_out, int out_size, void* d_ws, size_t ws_size,
                              hipStream_t stream) {
    const float* x    = (const float*)d_in[0];
    const float* Wr   = (const float*)d_in[1];
    const float* Wi   = (const float*)d_in[2];
    const float* Wj   = (const float*)d_in[3];
    const float* Wk   = (const float*)d_in[4];
    const float* bias = (const float*)d_in[5];
    float* out = (float*)d_out;

    const size_t xb_bytes = (size_t)M_DIM * K_DIM * 2;  // 64 MiB
    const size_t wb_bytes = (size_t)N_DIM * K_DIM * 2;  // 32 MiB

    if (ws_size >= xb_bytes + wb_bytes) {
        unsigned short* xbt = (unsigned short*)d_ws;
        unsigned short* wb  = (unsigned short*)((char*)d_ws + xb_bytes);
        cvt_x_t<<<64 * 64, 256, 0, stream>>>(x, xbt);
        prep_w_kernel<<<N_DIM * 2, 256, 0, stream>>>(Wr, Wi, Wj, Wk, wb);
        const int n_blocks = (M_DIM / 256) * (N_DIM / 256);  // 512
        qgemm_bf16<<<n_blocks, 512, 0, stream>>>(xbt, wb, bias, out);
    } else {
        const int n_blocks = (M_DIM / FBM) * (N_DIM / FBN);  // 2048
        qgemm_fb<<<n_blocks, 256, 0, stream>>>(x, Wr, Wi, Wj, Wk, bias, out);
    }
}

// Round 15
// 272.207 us; speedup vs baseline: 1.0700x; 1.0700x over previous
//
#include <hip/hip_runtime.h>
#include <hip/hip_bf16.h>

// QuaternionLinear = one 8192x4096x4096 GEMM vs Hamilton-assembled W.
// Round 15: faithful m201 8-phase template port. 2 K-tiles per iteration
// (even->buf0, odd->buf1: LDS addresses loop-invariant, zero per-tile VALU);
// per phase {asm ds_reads; 1-2 half-tile gld_lds stages; [lgkmcnt(8) if
// 12-read phase]; bare s_barrier; lgkmcnt(0)+sched_barrier; setprio; 16 MFMA;
// setprio; [vmcnt(4) at ph4/ph8]; bare s_barrier}. Staging calendar (verified
// ledger): ph1:Aod.h0 ph2:Aod.h1+Bev'.h0 ph3:Bev'.h1 ph5:Aev'.h0 ph6:Aev'.h1
// ph7:Bod'.h0 ph8:Bod'.h1. 0-conflict swizzle layout from R4/R8 (proven).

#define M_DIM 8192
#define N_DIM 4096
#define K_DIM 4096
#define BK 64
#define NT (K_DIM / BK)     // 64 K-tiles
#define NIT (NT / 2)        // 32 iterations

typedef __attribute__((ext_vector_type(8))) short bf16x8;
typedef __attribute__((ext_vector_type(4))) float f32x4;
typedef __attribute__((ext_vector_type(8))) unsigned short ushort8;

static __device__ __forceinline__ unsigned short f2bf(float f) {
    unsigned int u = __float_as_uint(f);
    return (unsigned short)((u + 0x7fffu + ((u >> 16) & 1u)) >> 16);
}
static __device__ __forceinline__ unsigned short f2bf_sgn(float f, unsigned int sg) {
    unsigned int u = __float_as_uint(f) ^ sg;
    return (unsigned short)((u + 0x7fffu + ((u >> 16) & 1u)) >> 16);
}

// ---------------- prep: x (fp32) -> xb (bf16 row-major) ----------------
__global__ __launch_bounds__(256) void cvt_x_kernel(const float* __restrict__ x,
                                                    unsigned short* __restrict__ xb) {
    int i = (blockIdx.x * 256 + threadIdx.x) * 8;
    f32x4 a = __builtin_nontemporal_load((const f32x4*)(x + i));
    f32x4 b = __builtin_nontemporal_load((const f32x4*)(x + i + 4));
    ushort8 o;
    o[0] = f2bf(a[0]); o[1] = f2bf(a[1]); o[2] = f2bf(a[2]); o[3] = f2bf(a[3]);
    o[4] = f2bf(b[0]); o[5] = f2bf(b[1]); o[6] = f2bf(b[2]); o[7] = f2bf(b[3]);
    *(ushort8*)(xb + i) = o;
}

// ---------------- prep: assemble Hamilton W (bf16 row-major) ----------------
__global__ __launch_bounds__(256) void prep_w_kernel(const float* __restrict__ Wr,
    const float* __restrict__ Wi, const float* __restrict__ Wj,
    const float* __restrict__ Wk, unsigned short* __restrict__ wb) {
    int row = blockIdx.x >> 1;
    int col = ((blockIdx.x & 1) * 256 + threadIdx.x) * 8;
    int p = row >> 10, q = col >> 10;
    int ci = p ^ q;
    const float* src = (ci == 0) ? Wr : (ci == 1) ? Wi : (ci == 2) ? Wj : Wk;
    unsigned int sg = ((0x428Eu >> (p * 4 + q)) & 1u) << 31;
    int so = (row & 1023) * 1024 + (col & 1023);
    f32x4 a = *(const f32x4*)(src + so);
    f32x4 b = *(const f32x4*)(src + so + 4);
    ushort8 o;
    o[0] = f2bf_sgn(a[0], sg); o[1] = f2bf_sgn(a[1], sg);
    o[2] = f2bf_sgn(a[2], sg); o[3] = f2bf_sgn(a[3], sg);
    o[4] = f2bf_sgn(b[0], sg); o[5] = f2bf_sgn(b[1], sg);
    o[6] = f2bf_sgn(b[2], sg); o[7] = f2bf_sgn(b[3], sg);
    *(ushort8*)(wb + row * 4096 + col) = o;
}

// ---------------- main GEMM ----------------
#define GLD16(gp, lp) __builtin_amdgcn_global_load_lds( \
    (const __attribute__((address_space(1))) void*)(gp), \
    (__attribute__((address_space(3))) void*)(lp), 16, 0, 0)

#define SB()  __builtin_amdgcn_sched_barrier(0)
#define DSR(dst, addr, imm) \
    asm volatile("ds_read_b128 %0, %1 offset:" imm : "=v"(dst) : "v"(addr))
#define MF(a, b, c) __builtin_amdgcn_mfma_f32_16x16x32_bf16(a, b, c, 0, 0, 0)

// B reads (8): all ni x ks for the tile; held in regs across its 4 phases.
#define RDB(B0, B1) do { \
    DSR(b0k0, B0, "0"); DSR(b1k0, B0, "2048"); \
    DSR(b2k0, B0, "4096"); DSR(b3k0, B0, "6144"); \
    DSR(b0k1, B1, "0"); DSR(b1k1, B1, "2048"); \
    DSR(b2k1, B1, "4096"); DSR(b3k1, B1, "6144"); } while (0)

// One phase: A-pair reads (4), stages (variadic), barrier, lgkm0, 16 MFMA,
// optional wait, barrier.
#define APHASE(A0, A1, I0, I1, ML, MH, WAITS, ...) do { \
    bf16x8 xk0l, xk0h, xk1l, xk1h; \
    DSR(xk0l, A0, I0); DSR(xk0h, A0, I1); \
    DSR(xk1l, A1, I0); DSR(xk1h, A1, I1); \
    __VA_ARGS__; \
    __builtin_amdgcn_s_barrier(); \
    asm volatile("s_waitcnt lgkmcnt(0)" ::: "memory"); SB(); \
    __builtin_amdgcn_s_setprio(1); \
    acc[ML][0] = MF(xk0l, b0k0, acc[ML][0]); acc[ML][1] = MF(xk0l, b1k0, acc[ML][1]); \
    acc[ML][2] = MF(xk0l, b2k0, acc[ML][2]); acc[ML][3] = MF(xk0l, b3k0, acc[ML][3]); \
    acc[MH][0] = MF(xk0h, b0k0, acc[MH][0]); acc[MH][1] = MF(xk0h, b1k0, acc[MH][1]); \
    acc[MH][2] = MF(xk0h, b2k0, acc[MH][2]); acc[MH][3] = MF(xk0h, b3k0, acc[MH][3]); \
    acc[ML][0] = MF(xk1l, b0k1, acc[ML][0]); acc[ML][1] = MF(xk1l, b1k1, acc[ML][1]); \
    acc[ML][2] = MF(xk1l, b2k1, acc[ML][2]); acc[ML][3] = MF(xk1l, b3k1, acc[ML][3]); \
    acc[MH][0] = MF(xk1h, b0k1, acc[MH][0]); acc[MH][1] = MF(xk1h, b1k1, acc[MH][1]); \
    acc[MH][2] = MF(xk1h, b2k1, acc[MH][2]); acc[MH][3] = MF(xk1h, b3k1, acc[MH][3]); \
    __builtin_amdgcn_s_setprio(0); \
    WAITS; \
    __builtin_amdgcn_s_barrier(); \
} while (0)

#define LGKM8() asm volatile("s_waitcnt lgkmcnt(8)" ::: "memory")
#define VMW(n)  asm volatile("s_waitcnt vmcnt(" #n ")" ::: "memory")
#define NOOP()  do {} while (0)

__global__ __launch_bounds__(512, 2) void qgemm_bf16(
    const unsigned short* __restrict__ A, const unsigned short* __restrict__ B,
    const float* __restrict__ bias, float* __restrict__ out)
{
    // [buf][op A=0/B=1][half][128 rows][64 cols] = 128 KiB. Content: 16B slot
    // s at row r holds kslot s^(r&7) (R4/R8-proven 0-conflict, both-sides).
    __shared__ __align__(16) unsigned short Lsh[2][2][2][128 * 64];

    int bid = blockIdx.x;
    int cpx = gridDim.x >> 3;                 // 512/8 = 64, bijective
    int wg  = (bid & 7) * cpx + (bid >> 3);
    int brow = (wg >> 4) * 256;               // 32 M-tiles
    int bcol = (wg & 15) * 256;               // 16 N-tiles

    int tid   = threadIdx.x;
    int lane  = tid & 63;
    int wid   = tid >> 6;
    int hA    = wid >> 2;                     // wave's A half
    int wn    = wid & 3;                      // wave's 64-col B band
    int fr    = lane & 15;
    int fslot = lane >> 4;
    unsigned e = (unsigned)(fr & 7);

    const unsigned short* Ag = A + (size_t)brow * K_DIM;
    const unsigned short* Bg = B + (size_t)bcol * K_DIM;

    // Loop-invariant LDS read addresses (8 VGPRs total).
    unsigned lds0 = (unsigned)(size_t)(__attribute__((address_space(3))) void*)Lsh;
    unsigned inrow = (((unsigned)fslot ^ e) << 4);
    unsigned vA0e = lds0 + (unsigned)(hA * 16384 + fr * 128) + inrow;           // buf0 A ks0
    unsigned vA1e = vA0e ^ 64u;                                                  // ks1
    unsigned vA0o = vA0e + 65536u, vA1o = vA1e + 65536u;                         // buf1
    unsigned vB0e = lds0 + 32768u
                  + (unsigned)((wn >> 1) * 16384 + ((wn & 1) * 64 + fr) * 128) + inrow;
    unsigned vB1e = vB0e ^ 64u;
    unsigned vB0o = vB0e + 65536u, vB1o = vB1e + 65536u;

    // Staging source offsets (elements): chunk c = {tid, 512+tid}.
    int soff0 = (tid >> 3) * K_DIM + (((tid & 7) ^ ((tid >> 3) & 7)) << 3);
    int soff1 = soff0 + 64 * K_DIM;

    f32x4 acc[8][4] = {};
    bf16x8 b0k0, b1k0, b2k0, b3k0, b0k1, b1k1, b2k1, b3k1;

    auto stgA = [&](int buf, int h, int t) {
        const unsigned short* g = Ag + (size_t)(h * 128) * K_DIM + t * BK;
        unsigned short* l = &Lsh[buf][0][h][0];
        GLD16(g + soff0, l + tid * 8);
        GLD16(g + soff1, l + 4096 + tid * 8);
    };
    auto stgB = [&](int buf, int h, int t) {
        const unsigned short* g = Bg + (size_t)(h * 128) * K_DIM + t * BK;
        unsigned short* l = &Lsh[buf][1][h][0];
        GLD16(g + soff0, l + tid * 8);
        GLD16(g + soff1, l + 4096 + tid * 8);
    };

    // Prologue: tile0 A+B (buf0), tile1 B (buf1). VM(4) leaves tile1-B flying.
    stgA(0, 0, 0); stgA(0, 1, 0); stgB(0, 0, 0); stgB(0, 1, 0);
    stgB(1, 0, 1); stgB(1, 1, 1);
    VMW(4); SB();
    __builtin_amdgcn_s_barrier();

    for (int n = 0; n < NIT; ++n) {
        int te = 2 * n + 2;                   // next even tile
        int to = 2 * n + 3;                   // next odd tile
        bool g1 = (n + 1 < NIT);

        // ======== even tile (buf0) ========
        RDB(vB0e, vB1e);
        // ph1: A q0; stage Aod.h0
        APHASE(vA0e, vA1e, "0", "2048", 0, 1, NOOP(),
               stgA(1, 0, 2 * n + 1); LGKM8());
        // ph2: A q1; stage Aod.h1 + Bev'.h0
        APHASE(vA0e, vA1e, "4096", "6144", 2, 3, NOOP(),
               stgA(1, 1, 2 * n + 1); if (g1) stgB(0, 0, te));
        // ph3: A q2; stage Bev'.h1
        APHASE(vA0e, vA1e, "8192", "10240", 4, 5, NOOP(),
               if (g1) stgB(0, 1, te));
        // ph4: A q3; counted vmcnt (Aod + older landed; Bev' flying)
        if (n < NIT - 1) {
            APHASE(vA0e, vA1e, "12288", "14336", 6, 7, VMW(4), NOOP());
        } else {
            APHASE(vA0e, vA1e, "12288", "14336", 6, 7, VMW(0), NOOP());
        }

        // ======== odd tile (buf1) ========
        RDB(vB0o, vB1o);
        // ph5: A q0; stage Aev'.h0
        APHASE(vA0o, vA1o, "0", "2048", 0, 1, NOOP(),
               if (g1) stgA(0, 0, te); LGKM8());
        // ph6: A q1; stage Aev'.h1
        APHASE(vA0o, vA1o, "4096", "6144", 2, 3, NOOP(),
               if (g1) stgA(0, 1, te));
        // ph7: A q2; stage Bod'.h0
        APHASE(vA0o, vA1o, "8192", "10240", 4, 5, NOOP(),
               if (g1) stgB(1, 0, to));
        // ph8: A q3; stage Bod'.h1; counted vmcnt (Aev'+Bev' landed)
        if (n < NIT - 1) {
            APHASE(vA0o, vA1o, "12288", "14336", 6, 7, VMW(4),
                   stgB(1, 1, to));
        } else {
            APHASE(vA0o, vA1o, "12288", "14336", 6, 7, VMW(0), NOOP());
        }
    }

    // epilogue: C/D col=lane&15, row=(lane>>4)*4+reg (verified R3-R10).
    int cr = (lane >> 4) << 2;
    int cc = lane & 15;
    #pragma unroll
    for (int ni = 0; ni < 4; ++ni) {
        int col = bcol + wn * 64 + ni * 16 + cc;
        float bv = bias[col];
        #pragma unroll
        for (int mi = 0; mi < 8; ++mi) {
            int r0 = brow + hA * 128 + mi * 16 + cr;
            #pragma unroll
            for (int r = 0; r < 4; ++r)
                __builtin_nontemporal_store(acc[mi][ni][r] + bv,
                                            &out[(size_t)(r0 + r) * N_DIM + col]);
        }
    }
}

// ---------------- fallback: reg-staged, no workspace (round-3, known-good) --
#define FBM 128
#define FBN 128
#define FBK 64
__global__ __launch_bounds__(256) void qgemm_fb(const float* __restrict__ x,
    const float* __restrict__ Wr, const float* __restrict__ Wi,
    const float* __restrict__ Wj, const float* __restrict__ Wk,
    const float* __restrict__ bias, float* __restrict__ out)
{
    __shared__ unsigned short As[FBM * FBK];
    __shared__ unsigned short Bs[FBN * FBK];

    int bid = blockIdx.x;
    int cpx = gridDim.x >> 3;
    int wg = (bid & 7) * cpx + (bid >> 3);
    int brow = (wg >> 5) * FBM;
    int bcol = (wg & 31) * FBN;

    int tid = threadIdx.x;
    int lane = tid & 63;
    int wv = tid >> 6;
    int wm = (wv >> 1) << 6;
    int wn = (wv & 1) << 6;
    int fr = lane & 15;
    int fk = (lane >> 4) << 3;

    int p = bcol >> 10;
    f32x4 acc[4][4] = {};

    for (int kt = 0; kt < K_DIM / FBK; ++kt) {
        int k0 = kt * FBK;
        int q = k0 >> 10;
        int ci = p ^ q;
        const float* wsrc = (ci == 0) ? Wr : (ci == 1) ? Wi : (ci == 2) ? Wj : Wk;
        unsigned int sg = ((0x428Eu >> (p * 4 + q)) & 1u) << 31;

        __syncthreads();
        #pragma unroll
        for (int i = 0; i < 4; ++i) {
            int c = i * 256 + tid;
            int row = c >> 3, colo = (c & 7) << 3;
            const float* s = x + (size_t)(brow + row) * K_DIM + k0 + colo;
            float4 a = *(const float4*)s;
            float4 b = *(const float4*)(s + 4);
            ushort8 o;
            o[0] = f2bf(a.x); o[1] = f2bf(a.y); o[2] = f2bf(a.z); o[3] = f2bf(a.w);
            o[4] = f2bf(b.x); o[5] = f2bf(b.y); o[6] = f2bf(b.z); o[7] = f2bf(b.w);
            *(ushort8*)(&As[c << 3]) = o;
        }
        #pragma unroll
        for (int i = 0; i < 4; ++i) {
            int c = i * 256 + tid;
            int row = c >> 3, colo = (c & 7) << 3;
            const float* s = wsrc + ((bcol + row) & 1023) * 1024 + ((k0 + colo) & 1023);
            float4 a = *(const float4*)s;
            float4 b = *(const float4*)(s + 4);
            ushort8 o;
            o[0] = f2bf_sgn(a.x, sg); o[1] = f2bf_sgn(a.y, sg);
            o[2] = f2bf_sgn(a.z, sg); o[3] = f2bf_sgn(a.w, sg);
            o[4] = f2bf_sgn(b.x, sg); o[5] = f2bf_sgn(b.y, sg);
            o[6] = f2bf_sgn(b.z, sg); o[7] = f2bf_sgn(b.w, sg);
            *(ushort8*)(&Bs[c << 3]) = o;
        }
        __syncthreads();

        #pragma unroll
        for (int ks = 0; ks < 2; ++ks) {
            bf16x8 af[4], bfr[4];
            #pragma unroll
            for (int m = 0; m < 4; ++m)
                af[m] = *(const bf16x8*)(&As[(wm + m * 16 + fr) * FBK + ks * 32 + fk]);
            #pragma unroll
            for (int n = 0; n < 4; ++n)
                bfr[n] = *(const bf16x8*)(&Bs[(wn + n * 16 + fr) * FBK + ks * 32 + fk]);
            #pragma unroll
            for (int m = 0; m < 4; ++m)
                #pragma unroll
                for (int n = 0; n < 4; ++n)
                    acc[m][n] = __builtin_amdgcn_mfma_f32_16x16x32_bf16(
                        af[m], bfr[n], acc[m][n], 0, 0, 0);
        }
    }

    int cr = (lane >> 4) << 2;
    int cc = lane & 15;
    #pragma unroll
    for (int n = 0; n < 4; ++n) {
        int col = bcol + wn + n * 16 + cc;
        float bv = bias[col];
        #pragma unroll
        for (int m = 0; m < 4; ++m) {
            int r0 = brow + wm + m * 16 + cr;
            #pragma unroll
            for (int r = 0; r < 4; ++r)
                out[(size_t)(r0 + r) * N_DIM + col] = acc[m][n][r] + bv;
        }
    }
}

extern "C" void kernel_launch(void* const* d_in, const int* in_sizes, int n_in,
                              void* d_out, int out_size, void* d_ws, size_t ws_size,
                              hipStream_t stream) {
    const float* x    = (const float*)d_in[0];
    const float* Wr   = (const float*)d_in[1];
    const float* Wi   = (const float*)d_in[2];
    const float* Wj   = (const float*)d_in[3];
    const float* Wk   = (const float*)d_in[4];
    const float* bias = (const float*)d_in[5];
    float* out = (float*)d_out;

    const size_t xb_bytes = (size_t)M_DIM * K_DIM * 2;  // 64 MiB
    const size_t wb_bytes = (size_t)N_DIM * K_DIM * 2;  // 32 MiB

    if (ws_size >= xb_bytes + wb_bytes) {
        unsigned short* xb = (unsigned short*)d_ws;
        unsigned short* wb = (unsigned short*)((char*)d_ws + xb_bytes);
        cvt_x_kernel<<<(M_DIM * K_DIM) / 2048, 256, 0, stream>>>(x, xb);
        prep_w_kernel<<<N_DIM * 2, 256, 0, stream>>>(Wr, Wi, Wj, Wk, wb);
        const int n_blocks = (M_DIM / 256) * (N_DIM / 256);  // 512
        qgemm_bf16<<<n_blocks, 512, 0, stream>>>(xb, wb, bias, out);
    } else {
        const int n_blocks = (M_DIM / FBM) * (N_DIM / FBN);  // 2048
        qgemm_fb<<<n_blocks, 256, 0, stream>>>(x, Wr, Wi, Wj, Wk, bias, out);
    }
}